// Round 8
// baseline (186.330 us; speedup 1.0000x reference)
//
#include <hip/hip_runtime.h>
#include <hip/hip_bf16.h>

#define SEQ  4096
#define HID  768
#define NH   12
#define HD   64
#define QKVN 2304
#define KVB  32
#define SPLIT 4
#define NT   ((SEQ/SPLIT)/KVB)   // 32 kv-tiles per block
#define LOG2E 1.44269504f

typedef __attribute__((ext_vector_type(8)))  short  short8;
typedef __attribute__((ext_vector_type(4)))  float  f32x4;
typedef __attribute__((ext_vector_type(16))) float  f32x16;

static __device__ __forceinline__ unsigned short bf16b(float x) {
  __hip_bfloat16 h = __float2bfloat16(x);
  return *reinterpret_cast<unsigned short*>(&h);
}
static __device__ __forceinline__ unsigned pkbf(float lo, float hi) {
  return (unsigned)bf16b(lo) | ((unsigned)bf16b(hi) << 16);
}
static __device__ __forceinline__ void store4(__hip_bfloat16* p, float a, float b, float c, float d) {
  unsigned long long v = (unsigned long long)pkbf(a, b) | ((unsigned long long)pkbf(c, d) << 32);
  *reinterpret_cast<unsigned long long*>(p) = v;
}
static __device__ __forceinline__ void gload16(const void* g, void* l) {
  __builtin_amdgcn_global_load_lds(
      (const __attribute__((address_space(1))) void*)g,
      (__attribute__((address_space(3))) void*)l, 16, 0, 0);
}

#if __has_builtin(__builtin_amdgcn_exp2f)
#define EXP2(x) __builtin_amdgcn_exp2f(x)
#else
#define EXP2(x) __expf((x) * 0.6931472f)
#endif

// half-exchange: x[lane] = lane<32 ? a : b[lane^32] ; y[lane] = lane<32 ? a[lane^32] : b
static __device__ __forceinline__ void swap32(unsigned a, unsigned b, unsigned& x, unsigned& y) {
#if __has_builtin(__builtin_amdgcn_permlane32_swap)
  auto r = __builtin_amdgcn_permlane32_swap((int)a, (int)b, false, false);
  x = (unsigned)r[0]; y = (unsigned)r[1];
#else
  unsigned pa = (unsigned)__shfl_xor((int)a, 32);
  unsigned pb = (unsigned)__shfl_xor((int)b, 32);
  int hi = (int)((threadIdx.x & 63) >> 5);
  x = hi ? pb : a;
  y = hi ? b : pa;
#endif
}

static __device__ __forceinline__ void cvt_store(float* p, float v) { *p = v; }
static __device__ __forceinline__ void cvt_store(__hip_bfloat16* p, float v) { *p = __float2bfloat16(v); }

// ---------------- prep: fp32 -> bf16 casts + weight/bias concat + mask*log2e ----
__global__ __launch_bounds__(256) void prep_kernel(
    const float* __restrict__ hs,
    const float* __restrict__ qw, const float* __restrict__ kw,
    const float* __restrict__ vw, const float* __restrict__ ow,
    const float* __restrict__ qb, const float* __restrict__ kb,
    const float* __restrict__ vb, const float* __restrict__ msk,
    __hip_bfloat16* __restrict__ Xb,
    __hip_bfloat16* __restrict__ Wqkv,
    __hip_bfloat16* __restrict__ Wo,
    float* __restrict__ bqkv,
    float* __restrict__ mask2)
{
  const int NX = SEQ*HID/4, NW = QKVN*HID/4, NO = HID*HID/4, NB = QKVN/4, NM = SEQ/4;
  int idx = blockIdx.x*256 + threadIdx.x;
  if (idx < NX) {
    float4 v = ((const float4*)hs)[idx];
    store4(Xb + idx*4, v.x, v.y, v.z, v.w);
  } else if (idx < NX + NW) {
    int f = (idx - NX)*4;
    int row = f / HID, col = f - row*HID;
    const float* src = (row < HID)   ? qw + row*HID + col
                     : (row < 2*HID) ? kw + (row-HID)*HID + col
                     :                 vw + (row-2*HID)*HID + col;
    float4 v = *(const float4*)src;
    store4(Wqkv + f, v.x, v.y, v.z, v.w);
  } else if (idx < NX + NW + NO) {
    int li = idx - NX - NW;
    float4 v = ((const float4*)ow)[li];
    store4(Wo + li*4, v.x, v.y, v.z, v.w);
  } else if (idx < NX + NW + NO + NB) {
    int f = (idx - NX - NW - NO)*4;
    const float* src = (f < HID) ? qb + f : (f < 2*HID) ? kb + (f-HID) : vb + (f-2*HID);
    *(float4*)(bqkv + f) = *(const float4*)src;
  } else if (idx < NX + NW + NO + NB + NM) {
    int f = (idx - NX - NW - NO - NB)*4;
    float4 v = *(const float4*)(msk + f);
    float4 o; o.x = v.x*LOG2E; o.y = v.y*LOG2E; o.z = v.z*LOG2E; o.w = v.w*LOG2E;
    *(float4*)(mask2 + f) = o;
  }
}

// ---------------- GEMM  C[M][N] = A[M][K] * B[N][K]^T + bias  (m97 structure) ----
template <typename OutT>
__global__ __launch_bounds__(256) void gemm_nt(
    const __hip_bfloat16* __restrict__ A,
    const __hip_bfloat16* __restrict__ B,
    const float* __restrict__ bias,
    OutT* __restrict__ C, int N, int K)
{
  __shared__ __align__(16) short As[128*32];
  __shared__ __align__(16) short Bs[128*32];
  const int tid  = threadIdx.x;
  const int lane = tid & 63;
  const int w    = tid >> 6;
  const int m0   = blockIdx.y * 128;
  const int n0   = blockIdx.x * 128;
  const int wrow = w >> 1, wcol = w & 1;
  const int l15  = lane & 15;
  const int k8   = (lane >> 4) * 8;

  f32x4 acc[4][4] = {};

  const int base0 = w*512;
  const int base1 = (4+w)*512;
  const int f0 = base0 + lane*8, f1 = base1 + lane*8;
  const __hip_bfloat16* Ap0 = A + (long)(m0 + (f0>>5))*K + (f0&31);
  const __hip_bfloat16* Ap1 = A + (long)(m0 + (f1>>5))*K + (f1&31);
  const __hip_bfloat16* Bp0 = B + (long)(n0 + (f0>>5))*K + (f0&31);
  const __hip_bfloat16* Bp1 = B + (long)(n0 + (f1>>5))*K + (f1&31);

  for (int k0 = 0; k0 < K; k0 += 32) {
    gload16(Ap0 + k0, As + base0);
    gload16(Ap1 + k0, As + base1);
    gload16(Bp0 + k0, Bs + base0);
    gload16(Bp1 + k0, Bs + base1);
    __syncthreads();

    short8 af[4], bfm[4];
#pragma unroll
    for (int mi = 0; mi < 4; ++mi)
      af[mi] = *(const short8*)&As[(wrow*64 + mi*16 + l15)*32 + k8];
#pragma unroll
    for (int ni = 0; ni < 4; ++ni)
      bfm[ni] = *(const short8*)&Bs[(wcol*64 + ni*16 + l15)*32 + k8];
#pragma unroll
    for (int mi = 0; mi < 4; ++mi)
#pragma unroll
      for (int ni = 0; ni < 4; ++ni)
        acc[mi][ni] = __builtin_amdgcn_mfma_f32_16x16x32_bf16(af[mi], bfm[ni], acc[mi][ni], 0, 0, 0);
    __syncthreads();
  }

  const int rbase = (lane >> 4) * 4;
#pragma unroll
  for (int mi = 0; mi < 4; ++mi)
#pragma unroll
    for (int ni = 0; ni < 4; ++ni) {
      int gm = m0 + wrow*64 + mi*16 + rbase;
      int gn = n0 + wcol*64 + ni*16 + l15;
      float bv = bias[gn];
#pragma unroll
      for (int r = 0; r < 4; ++r)
        cvt_store(&C[(long)(gm + r)*N + gn], acc[mi][ni][r] + bv);
    }
}

// ---------------- flash attention, KV-split + fixed-max softmax ---------------
// grid (SEQ/64, NH, SPLIT=4) = 3072 blocks; 128 thr = 2 waves; LDS 13312B ->
// 12 blocks/CU resident = SINGLE uniform pass (was 8 + tail).
// Two-barrier iter: compute (QK^T, softmax, PV from single VT buf) | bar1
// (lgkm only) | stage (VT<-V[t+1], gload K[t+1], prefetch mask/V) | bar2
// (vmcnt(6): retires exactly the K gloads; mask/V prefetches fly across).
__global__ __launch_bounds__(128, 4) void attn_fwd(
    const __hip_bfloat16* __restrict__ QKV,  // [SEQ][2304]
    const float* __restrict__ mask2,         // [SEQ], pre-scaled by log2e
    float* __restrict__ Oacc,                // [SEQ][HID]  (zeroed)
    float* __restrict__ Lacc)                // [NH][SEQ]   (zeroed)
{
  __shared__ __align__(16) char SMEM[13312];
  short* KsB = (short*)SMEM;            // 2 buffers x 2048 shorts (8KB)
  short* VTB = (short*)(SMEM + 8192);   // 1 buffer x 2560 shorts (5.12KB)
  float* Of  = (float*)SMEM;            // epilogue overlay [32][65] f32 (8.3KB)

  const int tid  = threadIdx.x;
  const int lane = tid & 63;
  const int wv   = tid >> 6;
  const int head = blockIdx.y;
  const int qt   = blockIdx.x;
  const int s0   = blockIdx.z * (SEQ/SPLIT);
  const int q0   = qt*64 + wv*32;
  const int ql   = lane & 31;
  const int hi   = lane >> 5;
  const float scale2 = 0.125f * LOG2E;

  // Q fragments: B-frag for S^T: col=q=ql, k=d = dc*16 + hi*8 + j
  short8 qf[4];
  {
    const __hip_bfloat16* qrow = QKV + (long)(q0+ql)*QKVN + head*HD + hi*8;
#pragma unroll
    for (int dc = 0; dc < 4; ++dc)
      qf[dc] = *(const short8*)(qrow + dc*16);
  }

  // K staging: 256 chunks of 16B; LDS chunk (krow,kcs) holds global chunk
  // kcs^(krow&7) (pre-swizzled source, m173 pattern).
  const __hip_bfloat16* kp[2];
#pragma unroll
  for (int i = 0; i < 2; ++i) {
    int slot = i*128 + tid;
    int krow = slot >> 3, kcs = slot & 7;
    kp[i] = QKV + (long)(s0 + krow)*QKVN + HID + head*HD + ((kcs ^ (krow & 7))*8);
  }

  // V staging: thread covers kv-pair (vkv2,vkv2+1), d-slice [vdb, vdb+8)
  const int vkv2 = (tid & 15)*2, vdb = (tid >> 4)*8;
  const __hip_bfloat16* vsrc = QKV + (long)(s0 + vkv2)*QKVN + 2*HID + head*HD + vdb;

  f32x16 oacc[2] = {};
  float lrun = 0.0f;
  float4 mgc[4], mgn[4];

  // ---- prologue: VT<-V[0]; gload K[0]; fence; prefetch mask[0] then V[1] ----
  short8 va = *(const short8*)(vsrc);
  short8 vb = *(const short8*)(vsrc + QKVN);
#pragma unroll
  for (int e = 0; e < 8; ++e) {
    unsigned w0 = (unsigned)(unsigned short)va[e] | ((unsigned)(unsigned short)vb[e] << 16);
    *(unsigned*)&VTB[(vdb + e)*40 + vkv2] = w0;
  }
  gload16(kp[0], KsB + (0*128 + wv*64)*8);
  gload16(kp[1], KsB + (1*128 + wv*64)*8);
  __builtin_amdgcn_sched_barrier(0);
  {
#pragma unroll
    for (int g = 0; g < 4; ++g)
      mgc[g] = *(const float4*)(mask2 + s0 + 8*g + 4*hi);
    const __hip_bfloat16* pv = vsrc + (long)KVB*QKVN;
    va = *(const short8*)(pv);
    vb = *(const short8*)(pv + QKVN);
  }
  asm volatile("s_waitcnt vmcnt(6) lgkmcnt(0)" ::: "memory");
  __builtin_amdgcn_s_barrier();
  __builtin_amdgcn_sched_barrier(0);

  for (int t = 0; t < NT; ++t) {
    short* ksC = KsB + (t & 1)*2048;

    // ---- compute phase (tile t) ----
    short8 kf[4];
#pragma unroll
    for (int dc = 0; dc < 4; ++dc)
      kf[dc] = *(const short8*)&ksC[ql*64 + (((dc*2 + hi) ^ (ql & 7))*8)];
    f32x16 sacc = {};
    __builtin_amdgcn_s_setprio(1);
#pragma unroll
    for (int dc = 0; dc < 4; ++dc)
      sacc = __builtin_amdgcn_mfma_f32_32x32x16_bf16(kf[dc], qf[dc], sacc, 0, 0, 0);
    __builtin_amdgcn_s_setprio(0);

    float p[16];
#pragma unroll
    for (int g = 0; g < 4; ++g) {
      p[4*g+0] = EXP2(sacc[4*g+0]*scale2 + mgc[g].x);
      p[4*g+1] = EXP2(sacc[4*g+1]*scale2 + mgc[g].y);
      p[4*g+2] = EXP2(sacc[4*g+2]*scale2 + mgc[g].z);
      p[4*g+3] = EXP2(sacc[4*g+3]*scale2 + mgc[g].w);
    }
    float sl0 = 0.f, sl1 = 0.f;
#pragma unroll
    for (int r = 0; r < 8; ++r) { sl0 += p[r]; sl1 += p[8+r]; }
    lrun += sl0 + sl1;

    unsigned pk[8];
#pragma unroll
    for (int u = 0; u < 8; ++u) pk[u] = pkbf(p[2*u], p[2*u+1]);
    unsigned b0[4], b1[4];
    swap32(pk[0], pk[2], b0[0], b0[2]);
    swap32(pk[1], pk[3], b0[1], b0[3]);
    swap32(pk[4], pk[6], b1[0], b1[2]);
    swap32(pk[5], pk[7], b1[1], b1[3]);
    union U { unsigned u[4]; short8 s; };
    U pb0{{b0[0], b0[1], b0[2], b0[3]}};   // P^T[kv 0..15][q]
    U pb1{{b1[0], b1[1], b1[2], b1[3]}};   // P^T[kv 16..31][q]

    short8 a00 = *(const short8*)&VTB[(ql)*40      + hi*8];
    short8 a01 = *(const short8*)&VTB[(ql)*40 + 16 + hi*8];
    short8 a10 = *(const short8*)&VTB[(32+ql)*40      + hi*8];
    short8 a11 = *(const short8*)&VTB[(32+ql)*40 + 16 + hi*8];

    __builtin_amdgcn_s_setprio(1);
    oacc[0] = __builtin_amdgcn_mfma_f32_32x32x16_bf16(a00, pb0.s, oacc[0], 0, 0, 0);
    oacc[0] = __builtin_amdgcn_mfma_f32_32x32x16_bf16(a01, pb1.s, oacc[0], 0, 0, 0);
    oacc[1] = __builtin_amdgcn_mfma_f32_32x32x16_bf16(a10, pb0.s, oacc[1], 0, 0, 0);
    oacc[1] = __builtin_amdgcn_mfma_f32_32x32x16_bf16(a11, pb1.s, oacc[1], 0, 0, 0);
    __builtin_amdgcn_s_setprio(0);

    // ---- barrier 1: all waves done reading VT (LDS ops drained) ----
    asm volatile("s_waitcnt lgkmcnt(0)" ::: "memory");
    __builtin_amdgcn_s_barrier();
    __builtin_amdgcn_sched_barrier(0);

    // ---- stage phase (tile t+1) ----
    if (t + 1 < NT) {
#pragma unroll
      for (int e = 0; e < 8; ++e) {
        unsigned w0 = (unsigned)(unsigned short)va[e] | ((unsigned)(unsigned short)vb[e] << 16);
        *(unsigned*)&VTB[(vdb + e)*40 + vkv2] = w0;
      }
      const long kn = (long)(t+1) * KVB * QKVN;
      short* ksN = KsB + ((t+1) & 1)*2048;
      gload16(kp[0] + kn, ksN + (0*128 + wv*64)*8);
      gload16(kp[1] + kn, ksN + (1*128 + wv*64)*8);
      __builtin_amdgcn_sched_barrier(0);
      // prefetch: masks FIRST (so softmax's auto-wait doesn't drain V), then V
      const float* mrowN = mask2 + s0 + (t+1)*KVB;
#pragma unroll
      for (int g = 0; g < 4; ++g)
        mgn[g] = *(const float4*)(mrowN + 8*g + 4*hi);
      const long kn2 = (long)(((t+2) < NT) ? (t+2) : (NT-1)) * KVB * QKVN;
      va = *(const short8*)(vsrc + kn2);
      vb = *(const short8*)(vsrc + kn2 + QKVN);
#pragma unroll
      for (int g = 0; g < 4; ++g) mgc[g] = mgn[g];
      // barrier 2: vmcnt(6) retires exactly K[t+1]; mask/V stay in flight
      asm volatile("s_waitcnt vmcnt(6) lgkmcnt(0)" ::: "memory");
      __builtin_amdgcn_s_barrier();
      __builtin_amdgcn_sched_barrier(0);
    }
  }

  // ---- epilogue: O^T -> O transpose via [32][65] overlay, 2 phases ----
  float lp = lrun + __shfl_xor(lrun, 32);
  if (hi == 0)
    unsafeAtomicAdd(&Lacc[head*SEQ + q0 + ql], lp);

#pragma unroll
  for (int ph = 0; ph < 2; ++ph) {
    __syncthreads();
    if (wv == ph) {
#pragma unroll
      for (int cb = 0; cb < 2; ++cb)
#pragma unroll
        for (int g = 0; g < 4; ++g)
#pragma unroll
          for (int r = 0; r < 4; ++r)
            Of[ql*65 + cb*32 + 8*g + 4*hi + r] = oacc[cb][4*g + r];
    }
    __syncthreads();
    float* obase = Oacc + (long)(qt*64 + ph*32)*HID + head*HD + lane;
#pragma unroll 4
    for (int r = 0; r < 16; ++r) {
      int row = wv*16 + r;
      unsafeAtomicAdd(obase + (long)row*HID, Of[row*65 + lane]);
    }
  }
}

// ---------------- finalize: ctx = Oacc / l ------------------------------------
__global__ __launch_bounds__(256) void finalize_kernel(
    const float* __restrict__ Oacc, const float* __restrict__ Lacc,
    __hip_bfloat16* __restrict__ ctx)
{
  int idx = blockIdx.x*256 + threadIdx.x;
  int q  = idx / (HID/4);
  int c4 = (idx - q*(HID/4))*4;
  float inv = 1.0f / Lacc[(c4 >> 6)*SEQ + q];
  float4 o = *(const float4*)&Oacc[(long)q*HID + c4];
  store4(ctx + (long)q*HID + c4, o.x*inv, o.y*inv, o.z*inv, o.w*inv);
}

// ---------------- launcher ----------------------------------------------------
extern "C" void kernel_launch(void* const* d_in, const int* in_sizes, int n_in,
                              void* d_out, int out_size, void* d_ws, size_t ws_size,
                              hipStream_t stream) {
  const float* hs  = (const float*)d_in[0];
  const float* msk = (const float*)d_in[1];
  const float* qw  = (const float*)d_in[2];
  const float* qb  = (const float*)d_in[3];
  const float* kw  = (const float*)d_in[4];
  const float* kb  = (const float*)d_in[5];
  const float* vw  = (const float*)d_in[6];
  const float* vb  = (const float*)d_in[7];
  const float* ow  = (const float*)d_in[8];
  const float* ob  = (const float*)d_in[9];

  char* ws = (char*)d_ws;
  __hip_bfloat16* Xb   = (__hip_bfloat16*)(ws);                 // 6,291,456 B
  __hip_bfloat16* Wqkv = (__hip_bfloat16*)(ws + 6291456);       // 3,538,944 B
  __hip_bfloat16* Wo   = (__hip_bfloat16*)(ws + 9830400);       // 1,179,648 B
  float*          bqkv = (float*)         (ws + 11010048);      //     9,216 B
  __hip_bfloat16* QKV  = (__hip_bfloat16*)(ws + 11019264);      // 18,874,368 B
  __hip_bfloat16* Ctx  = (__hip_bfloat16*)(ws + 29893632);      // 6,291,456 B
  float*          Oacc = (float*)         (ws + 36185088);      // 12,582,912 B
  float*          Lacc = (float*)         (ws + 48768000);      //    196,608 B
  float*          Mask2= (float*)         (ws + 48964608);      //     16,384 B

  hipMemsetAsync(Oacc, 0, 12582912 + 196608, stream);

  {
    const int total = SEQ*HID/4 + QKVN*HID/4 + HID*HID/4 + QKVN/4 + SEQ/4;
    prep_kernel<<<(total + 255)/256, 256, 0, stream>>>(hs, qw, kw, vw, ow, qb, kb, vb, msk,
                                                       Xb, Wqkv, Wo, bqkv, Mask2);
  }
  gemm_nt<__hip_bfloat16><<<dim3(QKVN/128, SEQ/128), 256, 0, stream>>>(Xb, Wqkv, bqkv, QKV, QKVN, HID);
  attn_fwd<<<dim3(SEQ/64, NH, SPLIT), 128, 0, stream>>>(QKV, Mask2, Oacc, Lacc);
  finalize_kernel<<<(SEQ*HID/4)/256, 256, 0, stream>>>(Oacc, Lacc, Ctx);
  gemm_nt<float><<<dim3(HID/128, SEQ/128), 256, 0, stream>>>(Ctx, Wo, ob, (float*)d_out, HID, HID);
}

// Round 9
// 170.518 us; speedup vs baseline: 1.0927x; 1.0927x over previous
//
#include <hip/hip_runtime.h>
#include <hip/hip_bf16.h>

#define SEQ  4096
#define HID  768
#define NH   12
#define HD   64
#define QKVN 2304
#define KVB  32
#define SPLIT 4
#define NT   ((SEQ/SPLIT)/KVB)   // 32 kv-tiles per block
#define LOG2E 1.44269504f

typedef __attribute__((ext_vector_type(8)))  short  short8;
typedef __attribute__((ext_vector_type(4)))  short  s16x4;
typedef __attribute__((ext_vector_type(4)))  float  f32x4;
typedef __attribute__((ext_vector_type(16))) float  f32x16;

static __device__ __forceinline__ unsigned short bf16b(float x) {
  __hip_bfloat16 h = __float2bfloat16(x);
  return *reinterpret_cast<unsigned short*>(&h);
}
static __device__ __forceinline__ unsigned pkbf(float lo, float hi) {
  return (unsigned)bf16b(lo) | ((unsigned)bf16b(hi) << 16);
}
static __device__ __forceinline__ void store4(__hip_bfloat16* p, float a, float b, float c, float d) {
  unsigned long long v = (unsigned long long)pkbf(a, b) | ((unsigned long long)pkbf(c, d) << 32);
  *reinterpret_cast<unsigned long long*>(p) = v;
}
static __device__ __forceinline__ void gload16(const void* g, void* l) {
  __builtin_amdgcn_global_load_lds(
      (const __attribute__((address_space(1))) void*)g,
      (__attribute__((address_space(3))) void*)l, 16, 0, 0);
}

#if __has_builtin(__builtin_amdgcn_exp2f)
#define EXP2(x) __builtin_amdgcn_exp2f(x)
#else
#define EXP2(x) __expf((x) * 0.6931472f)
#endif

// half-exchange: x[lane] = lane<32 ? a : b[lane^32] ; y[lane] = lane<32 ? a[lane^32] : b
static __device__ __forceinline__ void swap32(unsigned a, unsigned b, unsigned& x, unsigned& y) {
#if __has_builtin(__builtin_amdgcn_permlane32_swap)
  auto r = __builtin_amdgcn_permlane32_swap((int)a, (int)b, false, false);
  x = (unsigned)r[0]; y = (unsigned)r[1];
#else
  unsigned pa = (unsigned)__shfl_xor((int)a, 32);
  unsigned pb = (unsigned)__shfl_xor((int)b, 32);
  int hi = (int)((threadIdx.x & 63) >> 5);
  x = hi ? pb : a;
  y = hi ? b : pa;
#endif
}

static __device__ __forceinline__ void cvt_store(float* p, float v) { *p = v; }
static __device__ __forceinline__ void cvt_store(__hip_bfloat16* p, float v) { *p = __float2bfloat16(v); }

// ---------------- prep: fp32 -> bf16 casts + weight/bias concat + mask*log2e ----
__global__ __launch_bounds__(256) void prep_kernel(
    const float* __restrict__ hs,
    const float* __restrict__ qw, const float* __restrict__ kw,
    const float* __restrict__ vw, const float* __restrict__ ow,
    const float* __restrict__ qb, const float* __restrict__ kb,
    const float* __restrict__ vb, const float* __restrict__ msk,
    __hip_bfloat16* __restrict__ Xb,
    __hip_bfloat16* __restrict__ Wqkv,
    __hip_bfloat16* __restrict__ Wo,
    float* __restrict__ bqkv,
    float* __restrict__ mask2)
{
  const int NX = SEQ*HID/4, NW = QKVN*HID/4, NO = HID*HID/4, NB = QKVN/4, NM = SEQ/4;
  int idx = blockIdx.x*256 + threadIdx.x;
  if (idx < NX) {
    float4 v = ((const float4*)hs)[idx];
    store4(Xb + idx*4, v.x, v.y, v.z, v.w);
  } else if (idx < NX + NW) {
    int f = (idx - NX)*4;
    int row = f / HID, col = f - row*HID;
    const float* src = (row < HID)   ? qw + row*HID + col
                     : (row < 2*HID) ? kw + (row-HID)*HID + col
                     :                 vw + (row-2*HID)*HID + col;
    float4 v = *(const float4*)src;
    store4(Wqkv + f, v.x, v.y, v.z, v.w);
  } else if (idx < NX + NW + NO) {
    int li = idx - NX - NW;
    float4 v = ((const float4*)ow)[li];
    store4(Wo + li*4, v.x, v.y, v.z, v.w);
  } else if (idx < NX + NW + NO + NB) {
    int f = (idx - NX - NW - NO)*4;
    const float* src = (f < HID) ? qb + f : (f < 2*HID) ? kb + (f-HID) : vb + (f-2*HID);
    *(float4*)(bqkv + f) = *(const float4*)src;
  } else if (idx < NX + NW + NO + NB + NM) {
    int f = (idx - NX - NW - NO - NB)*4;
    float4 v = *(const float4*)(msk + f);
    float4 o; o.x = v.x*LOG2E; o.y = v.y*LOG2E; o.z = v.z*LOG2E; o.w = v.w*LOG2E;
    *(float4*)(mask2 + f) = o;
  }
}

// ---------------- GEMM  C[M][N] = A[M][K] * B[N][K]^T + bias  (m97 structure) ----
template <typename OutT>
__global__ __launch_bounds__(256) void gemm_nt(
    const __hip_bfloat16* __restrict__ A,
    const __hip_bfloat16* __restrict__ B,
    const float* __restrict__ bias,
    OutT* __restrict__ C, int N, int K)
{
  __shared__ __align__(16) short As[128*32];
  __shared__ __align__(16) short Bs[128*32];
  const int tid  = threadIdx.x;
  const int lane = tid & 63;
  const int w    = tid >> 6;
  const int m0   = blockIdx.y * 128;
  const int n0   = blockIdx.x * 128;
  const int wrow = w >> 1, wcol = w & 1;
  const int l15  = lane & 15;
  const int k8   = (lane >> 4) * 8;

  f32x4 acc[4][4] = {};

  const int base0 = w*512;
  const int base1 = (4+w)*512;
  const int f0 = base0 + lane*8, f1 = base1 + lane*8;
  const __hip_bfloat16* Ap0 = A + (long)(m0 + (f0>>5))*K + (f0&31);
  const __hip_bfloat16* Ap1 = A + (long)(m0 + (f1>>5))*K + (f1&31);
  const __hip_bfloat16* Bp0 = B + (long)(n0 + (f0>>5))*K + (f0&31);
  const __hip_bfloat16* Bp1 = B + (long)(n0 + (f1>>5))*K + (f1&31);

  for (int k0 = 0; k0 < K; k0 += 32) {
    gload16(Ap0 + k0, As + base0);
    gload16(Ap1 + k0, As + base1);
    gload16(Bp0 + k0, Bs + base0);
    gload16(Bp1 + k0, Bs + base1);
    __syncthreads();

    short8 af[4], bfm[4];
#pragma unroll
    for (int mi = 0; mi < 4; ++mi)
      af[mi] = *(const short8*)&As[(wrow*64 + mi*16 + l15)*32 + k8];
#pragma unroll
    for (int ni = 0; ni < 4; ++ni)
      bfm[ni] = *(const short8*)&Bs[(wcol*64 + ni*16 + l15)*32 + k8];
#pragma unroll
    for (int mi = 0; mi < 4; ++mi)
#pragma unroll
      for (int ni = 0; ni < 4; ++ni)
        acc[mi][ni] = __builtin_amdgcn_mfma_f32_16x16x32_bf16(af[mi], bfm[ni], acc[mi][ni], 0, 0, 0);
    __syncthreads();
  }

  const int rbase = (lane >> 4) * 4;
#pragma unroll
  for (int mi = 0; mi < 4; ++mi)
#pragma unroll
    for (int ni = 0; ni < 4; ++ni) {
      int gm = m0 + wrow*64 + mi*16 + rbase;
      int gn = n0 + wcol*64 + ni*16 + l15;
      float bv = bias[gn];
#pragma unroll
      for (int r = 0; r < 4; ++r)
        cvt_store(&C[(long)(gm + r)*N + gn], acc[mi][ni][r] + bv);
    }
}

// ---------------- flash attention, KV-split + fixed-max softmax ---------------
// grid (SEQ/128, NH, SPLIT=4) = 1536 blocks; 256 thr = 4 waves (occupancy is
// WG-slot-limited, not LDS-limited -> pack more waves per WG; r5/r8 evidence).
// Each wave owns 32 q-rows; KVB=32 tile shared. r7's single-barrier counted-
// vmcnt loop: stage {VT[nxt] writes, 1 K gload} | fence | prefetch {4 mask,
// 2 V} | compute | vmcnt(6)+barrier (retires exactly the K gload).
__global__ __launch_bounds__(256, 4) void attn_fwd(
    const __hip_bfloat16* __restrict__ QKV,  // [SEQ][2304]
    const float* __restrict__ mask2,         // [SEQ], pre-scaled by log2e
    float* __restrict__ Oacc,                // [SEQ][HID]  (zeroed)
    float* __restrict__ Lacc)                // [NH][SEQ]   (zeroed)
{
  __shared__ __align__(16) char SMEM[18432];
  short* KsB = (short*)SMEM;            // 2 buffers x 2048 shorts (8KB)
  short* VTB = (short*)(SMEM + 8192);   // 2 buffers x 2560 shorts (10.25KB)
  float* Of  = (float*)SMEM;            // epilogue overlay [64][65] f32 (16.6KB)

  const int tid  = threadIdx.x;
  const int lane = tid & 63;
  const int wv   = tid >> 6;            // 0..3
  const int head = blockIdx.y;
  const int qt   = blockIdx.x;
  const int s0   = blockIdx.z * (SEQ/SPLIT);
  const int q0   = qt*128 + wv*32;
  const int ql   = lane & 31;
  const int hi   = lane >> 5;
  const float scale2 = 0.125f * LOG2E;

  // Q fragments: B-frag for S^T: col=q=ql, k=d = dc*16 + hi*8 + j
  short8 qf[4];
  {
    const __hip_bfloat16* qrow = QKV + (long)(q0+ql)*QKVN + head*HD + hi*8;
#pragma unroll
    for (int dc = 0; dc < 4; ++dc)
      qf[dc] = *(const short8*)(qrow + dc*16);
  }

  // K staging: 256 chunks of 16B, one per thread; LDS chunk (krow,kcs) holds
  // global chunk kcs^(krow&7) (pre-swizzled source, m173). Wave wv covers
  // chunks [wv*64, +64) -> wave-uniform LDS base + lane*16.
  const __hip_bfloat16* kp;
  {
    int krow = tid >> 3, kcs = tid & 7;
    kp = QKV + (long)(s0 + krow)*QKVN + HID + head*HD + ((kcs ^ (krow & 7))*8);
  }

  // V staging: thread covers kv-pair (vkv2,vkv2+1), d-slice [vdb4, vdb4+4)
  const int vkv2 = (tid & 15)*2, vdb4 = (tid >> 4)*4;
  const __hip_bfloat16* vsrc = QKV + (long)(s0 + vkv2)*QKVN + 2*HID + head*HD + vdb4;

  f32x16 oacc[2] = {};
  float lrun = 0.0f;
  float4 mgc[4], mgn[4];

  // ---- prologue: VT[0]<-V[0]; gload K[0]; fence; prefetch mask[0], V[1] ----
  s16x4 va = *(const s16x4*)(vsrc);
  s16x4 vb = *(const s16x4*)(vsrc + QKVN);
#pragma unroll
  for (int e = 0; e < 4; ++e) {
    unsigned w0 = (unsigned)(unsigned short)va[e] | ((unsigned)(unsigned short)vb[e] << 16);
    *(unsigned*)&VTB[(vdb4 + e)*40 + vkv2] = w0;
  }
  gload16(kp, KsB + wv*512);
  __builtin_amdgcn_sched_barrier(0);
  {
#pragma unroll
    for (int g = 0; g < 4; ++g)
      mgc[g] = *(const float4*)(mask2 + s0 + 8*g + 4*hi);
    const __hip_bfloat16* pv = vsrc + (long)KVB*QKVN;
    va = *(const s16x4*)(pv);
    vb = *(const s16x4*)(pv + QKVN);
  }
  asm volatile("s_waitcnt vmcnt(6) lgkmcnt(0)" ::: "memory");
  __builtin_amdgcn_s_barrier();
  __builtin_amdgcn_sched_barrier(0);

  for (int t = 0; t < NT; ++t) {
    short* ksC = KsB + (t & 1)*2048;
    short* vtC = VTB + (t & 1)*2560;
    short* vtN = VTB + ((t+1) & 1)*2560;

    // 1. VT[nxt] <- regs (V tile t+1)
#pragma unroll
    for (int e = 0; e < 4; ++e) {
      unsigned w0 = (unsigned)(unsigned short)va[e] | ((unsigned)(unsigned short)vb[e] << 16);
      *(unsigned*)&vtN[(vdb4 + e)*40 + vkv2] = w0;
    }
    // 2. gload K[t+1] -> Ks[nxt]  (skipped last iter -> epilogue overlay safe)
    if (t + 1 < NT) {
      const long kn = (long)(t+1) * KVB * QKVN;
      gload16(kp + kn, KsB + ((t+1) & 1)*2048 + wv*512);
    }
    __builtin_amdgcn_sched_barrier(0);
    // 3. prefetch mask[t+1] (4 VMEM) then V[t+2] (2 VMEM)
    {
      const float* mrowN = mask2 + s0 + (((t+1) < NT) ? (t+1) : t)*KVB;
#pragma unroll
      for (int g = 0; g < 4; ++g)
        mgn[g] = *(const float4*)(mrowN + 8*g + 4*hi);
      const long kn2 = (long)(((t+2) < NT) ? (t+2) : (NT-1)) * KVB * QKVN;
      va = *(const s16x4*)(vsrc + kn2);
      vb = *(const s16x4*)(vsrc + kn2 + QKVN);
    }

    // 5. K frags + QK^T  (S^T = K . Q^T)
    short8 kf[4];
#pragma unroll
    for (int dc = 0; dc < 4; ++dc)
      kf[dc] = *(const short8*)&ksC[ql*64 + (((dc*2 + hi) ^ (ql & 7))*8)];
    f32x16 sacc = {};
#pragma unroll
    for (int dc = 0; dc < 4; ++dc)
      sacc = __builtin_amdgcn_mfma_f32_32x32x16_bf16(kf[dc], qf[dc], sacc, 0, 0, 0);

    // 6. fixed-max softmax: p = exp2(s*scale2 + m2); lane-local l
    float p[16];
#pragma unroll
    for (int g = 0; g < 4; ++g) {
      p[4*g+0] = EXP2(sacc[4*g+0]*scale2 + mgc[g].x);
      p[4*g+1] = EXP2(sacc[4*g+1]*scale2 + mgc[g].y);
      p[4*g+2] = EXP2(sacc[4*g+2]*scale2 + mgc[g].z);
      p[4*g+3] = EXP2(sacc[4*g+3]*scale2 + mgc[g].w);
    }
    float sl0 = 0.f, sl1 = 0.f;
#pragma unroll
    for (int r = 0; r < 8; ++r) { sl0 += p[r]; sl1 += p[8+r]; }
    lrun += sl0 + sl1;

    // 7. pack P^T -> B-frags via permlane32_swap half-exchange
    unsigned pk[8];
#pragma unroll
    for (int u = 0; u < 8; ++u) pk[u] = pkbf(p[2*u], p[2*u+1]);
    unsigned b0[4], b1[4];
    swap32(pk[0], pk[2], b0[0], b0[2]);
    swap32(pk[1], pk[3], b0[1], b0[3]);
    swap32(pk[4], pk[6], b1[0], b1[2]);
    swap32(pk[5], pk[7], b1[1], b1[3]);
    union U { unsigned u[4]; short8 s; };
    U pb0{{b0[0], b0[1], b0[2], b0[3]}};   // P^T[kv 0..15][q]
    U pb1{{b1[0], b1[1], b1[2], b1[3]}};   // P^T[kv 16..31][q]

    // 8. PV: O^T += V^T . P^T
    short8 a00 = *(const short8*)&vtC[(ql)*40      + hi*8];
    short8 a01 = *(const short8*)&vtC[(ql)*40 + 16 + hi*8];
    short8 a10 = *(const short8*)&vtC[(32+ql)*40      + hi*8];
    short8 a11 = *(const short8*)&vtC[(32+ql)*40 + 16 + hi*8];

    oacc[0] = __builtin_amdgcn_mfma_f32_32x32x16_bf16(a00, pb0.s, oacc[0], 0, 0, 0);
    oacc[0] = __builtin_amdgcn_mfma_f32_32x32x16_bf16(a01, pb1.s, oacc[0], 0, 0, 0);
    oacc[1] = __builtin_amdgcn_mfma_f32_32x32x16_bf16(a10, pb0.s, oacc[1], 0, 0, 0);
    oacc[1] = __builtin_amdgcn_mfma_f32_32x32x16_bf16(a11, pb1.s, oacc[1], 0, 0, 0);

    // rotate mask prefetch
#pragma unroll
    for (int g = 0; g < 4; ++g) mgc[g] = mgn[g];

    // counted-vmcnt barrier: retires exactly the K[t+1] gload; mask/V fly on
    asm volatile("s_waitcnt vmcnt(6) lgkmcnt(0)" ::: "memory");
    __builtin_amdgcn_s_barrier();
    __builtin_amdgcn_sched_barrier(0);
  }

  // ---- epilogue: O^T -> O transpose via [64][65] overlay, 2 phases ----
  float lp = lrun + __shfl_xor(lrun, 32);
  if (hi == 0)
    unsafeAtomicAdd(&Lacc[head*SEQ + q0 + ql], lp);

#pragma unroll
  for (int ph = 0; ph < 2; ++ph) {
    __syncthreads();
    if ((wv >> 1) == ph) {
      int row = (wv & 1)*32 + ql;
#pragma unroll
      for (int cb = 0; cb < 2; ++cb)
#pragma unroll
        for (int g = 0; g < 4; ++g)
#pragma unroll
          for (int r = 0; r < 4; ++r)
            Of[row*65 + cb*32 + 8*g + 4*hi + r] = oacc[cb][4*g + r];
    }
    __syncthreads();
    float* obase = Oacc + (long)(qt*128 + ph*64)*HID + head*HD + lane;
#pragma unroll 4
    for (int r = 0; r < 16; ++r) {
      int row = wv*16 + r;
      unsafeAtomicAdd(obase + (long)row*HID, Of[row*65 + lane]);
    }
  }
}

// ---------------- finalize: ctx = Oacc / l ------------------------------------
__global__ __launch_bounds__(256) void finalize_kernel(
    const float* __restrict__ Oacc, const float* __restrict__ Lacc,
    __hip_bfloat16* __restrict__ ctx)
{
  int idx = blockIdx.x*256 + threadIdx.x;
  int q  = idx / (HID/4);
  int c4 = (idx - q*(HID/4))*4;
  float inv = 1.0f / Lacc[(c4 >> 6)*SEQ + q];
  float4 o = *(const float4*)&Oacc[(long)q*HID + c4];
  store4(ctx + (long)q*HID + c4, o.x*inv, o.y*inv, o.z*inv, o.w*inv);
}

// ---------------- launcher ----------------------------------------------------
extern "C" void kernel_launch(void* const* d_in, const int* in_sizes, int n_in,
                              void* d_out, int out_size, void* d_ws, size_t ws_size,
                              hipStream_t stream) {
  const float* hs  = (const float*)d_in[0];
  const float* msk = (const float*)d_in[1];
  const float* qw  = (const float*)d_in[2];
  const float* qb  = (const float*)d_in[3];
  const float* kw  = (const float*)d_in[4];
  const float* kb  = (const float*)d_in[5];
  const float* vw  = (const float*)d_in[6];
  const float* vb  = (const float*)d_in[7];
  const float* ow  = (const float*)d_in[8];
  const float* ob  = (const float*)d_in[9];

  char* ws = (char*)d_ws;
  __hip_bfloat16* Xb   = (__hip_bfloat16*)(ws);                 // 6,291,456 B
  __hip_bfloat16* Wqkv = (__hip_bfloat16*)(ws + 6291456);       // 3,538,944 B
  __hip_bfloat16* Wo   = (__hip_bfloat16*)(ws + 9830400);       // 1,179,648 B
  float*          bqkv = (float*)         (ws + 11010048);      //     9,216 B
  __hip_bfloat16* QKV  = (__hip_bfloat16*)(ws + 11019264);      // 18,874,368 B
  __hip_bfloat16* Ctx  = (__hip_bfloat16*)(ws + 29893632);      // 6,291,456 B
  float*          Oacc = (float*)         (ws + 36185088);      // 12,582,912 B
  float*          Lacc = (float*)         (ws + 48768000);      //    196,608 B
  float*          Mask2= (float*)         (ws + 48964608);      //     16,384 B

  hipMemsetAsync(Oacc, 0, 12582912 + 196608, stream);

  {
    const int total = SEQ*HID/4 + QKVN*HID/4 + HID*HID/4 + QKVN/4 + SEQ/4;
    prep_kernel<<<(total + 255)/256, 256, 0, stream>>>(hs, qw, kw, vw, ow, qb, kb, vb, msk,
                                                       Xb, Wqkv, Wo, bqkv, Mask2);
  }
  gemm_nt<__hip_bfloat16><<<dim3(QKVN/128, SEQ/128), 256, 0, stream>>>(Xb, Wqkv, bqkv, QKV, QKVN, HID);
  attn_fwd<<<dim3(SEQ/128, NH, SPLIT), 256, 0, stream>>>(QKV, Mask2, Oacc, Lacc);
  finalize_kernel<<<(SEQ*HID/4)/256, 256, 0, stream>>>(Oacc, Lacc, Ctx);
  gemm_nt<float><<<dim3(HID/128, SEQ/128), 256, 0, stream>>>(Ctx, Wo, ob, (float*)d_out, HID, HID);
}